// Round 1
// baseline (4925.298 us; speedup 1.0000x reference)
//
#include <hip/hip_runtime.h>
#include <math.h>
#include <stdint.h>

#define NB 8
#define CIN 512
#define HW 4096
#define ANUM 9
#define NANC 36864
#define PRE 2000
#define POST 300

// d_out float offsets
#define OUT_LOCS   0
#define OUT_SCORES 1179648
#define OUT_ROIS   1769472
#define OUT_RIDX   1779072
#define OUT_ANC    1781472

// ---------------- K0: anchors ----------------
__global__ void anchor_kernel(float* __restrict__ out) {
  int i = blockIdx.x * 256 + threadIdx.x;
  if (i >= NANC) return;
  int s = i / 9, a = i - s * 9;
  int y = s >> 6, x = s & 63;
  int ri = a / 3, si = a - ri * 3;
  double r = (ri == 0) ? 0.5 : (ri == 1 ? 1.0 : 2.0);
  double sc = (si == 0) ? 8.0 : (si == 1 ? 16.0 : 32.0);
  double hh = 16.0 * sc * sqrt(r);
  double ww = 16.0 * sc * sqrt(1.0 / r);
  float a0 = (float)(8.0 - hh * 0.5);
  float a1 = (float)(8.0 - ww * 0.5);
  float a2 = (float)(8.0 + hh * 0.5);
  float a3 = (float)(8.0 + ww * 0.5);
  float sy = (float)(y * 16), sx = (float)(x * 16);
  out[OUT_ANC + i * 4 + 0] = a0 + sy;
  out[OUT_ANC + i * 4 + 1] = a1 + sx;
  out[OUT_ANC + i * 4 + 2] = a2 + sy;
  out[OUT_ANC + i * 4 + 3] = a3 + sx;
}

// ---------------- K1: conv3x3 + bias + relu ----------------
// grid 1024: ocb (32) fastest, tile (4), n (8). 256 threads = 16x16, each 2x2 px x 16 oc.
__global__ __launch_bounds__(256) void conv3_kernel(
    const float* __restrict__ x, const float* __restrict__ w,
    const float* __restrict__ bias, float* __restrict__ h) {
  __shared__ float xs[4][34][34];
  __shared__ float wls[4][9][16];
  int blk = blockIdx.x;
  int ocb = blk & 31;
  int t = (blk >> 5) & 3;
  int n = blk >> 7;
  int ty0 = (t >> 1) * 32, tx0 = (t & 1) * 32;
  int tid = threadIdx.x;
  int ty = tid >> 4, tx = tid & 15;

  float acc[16][2][2];
#pragma unroll
  for (int o = 0; o < 16; o++)
#pragma unroll
    for (int p = 0; p < 2; p++)
#pragma unroll
      for (int q = 0; q < 2; q++) acc[o][p][q] = 0.f;

  const float* xn = x + (size_t)n * CIN * HW;
  for (int ic0 = 0; ic0 < CIN; ic0 += 4) {
    for (int l = tid; l < 4 * 34 * 34; l += 256) {
      int ic = l / 1156; int rem = l - ic * 1156;
      int dy = rem / 34; int dx = rem - dy * 34;
      int gy = ty0 - 1 + dy, gx = tx0 - 1 + dx;
      float v = 0.f;
      if ((unsigned)gy < 64u && (unsigned)gx < 64u)
        v = xn[(size_t)(ic0 + ic) * HW + gy * 64 + gx];
      (&xs[0][0][0])[l] = v;
    }
    for (int l = tid; l < 4 * 9 * 16; l += 256) {
      int ic = l / 144; int rem = l - ic * 144;
      int k = rem / 16; int o = rem - k * 16;
      wls[ic][k][o] = w[((size_t)(ocb * 16 + o) * CIN + ic0 + ic) * 9 + k];
    }
    __syncthreads();
#pragma unroll
    for (int ic = 0; ic < 4; ++ic) {
      float xv[4][4];
#pragma unroll
      for (int r = 0; r < 4; r++)
#pragma unroll
        for (int c = 0; c < 4; c++) xv[r][c] = xs[ic][ty * 2 + r][tx * 2 + c];
#pragma unroll
      for (int k = 0; k < 9; k++) {
        int ky = k / 3, kx = k - ky * 3;
        float wv[16];
#pragma unroll
        for (int o = 0; o < 16; o++) wv[o] = wls[ic][k][o];
#pragma unroll
        for (int o = 0; o < 16; o++)
#pragma unroll
          for (int p = 0; p < 2; p++)
#pragma unroll
            for (int q = 0; q < 2; q++)
              acc[o][p][q] = fmaf(xv[p + ky][q + kx], wv[o], acc[o][p][q]);
      }
    }
    __syncthreads();
  }
#pragma unroll
  for (int o = 0; o < 16; o++) {
    int oc = ocb * 16 + o;
    float bv = bias[oc];
#pragma unroll
    for (int p = 0; p < 2; p++)
#pragma unroll
      for (int q = 0; q < 2; q++) {
        int oy = ty0 + ty * 2 + p, ox = tx0 + tx * 2 + q;
        float v = acc[o][p][q] + bv;
        h[((size_t)n * CIN + oc) * HW + oy * 64 + ox] = v > 0.f ? v : 0.f;
      }
  }
}

// ---------------- K2: 1x1 heads + transpose + fg + box decode ----------------
// grid 256: 128 positions/block, 256 threads = 128 pos x 2 c-slices of 256 ch
__global__ __launch_bounds__(256) void heads_kernel(
    const float* __restrict__ h, const float* __restrict__ sw,
    const float* __restrict__ sb, const float* __restrict__ lw,
    const float* __restrict__ lb, float* __restrict__ out,
    float* __restrict__ fgm, float* __restrict__ boxes) {
  __shared__ float wlds[2][64][56];
  __shared__ float part[128][56];
  int tid = threadIdx.x;
  int sl = tid >> 7;
  int pl = tid & 127;
  int blk = blockIdx.x;
  int n = blk >> 5;
  int s0 = (blk & 31) * 128;

  float acc[54];
#pragma unroll
  for (int k = 0; k < 54; k++) acc[k] = 0.f;

  for (int cc = 0; cc < 256; cc += 64) {
    for (int l = tid; l < 2 * 64 * 54; l += 256) {
      int slc = l / (64 * 54); int rem = l - slc * 64 * 54;
      int cl = rem / 54; int k = rem - cl * 54;
      int c = slc * 256 + cc + cl;
      wlds[slc][cl][k] = (k < 18) ? sw[k * CIN + c] : lw[(k - 18) * CIN + c];
    }
    __syncthreads();
    int cbase = sl * 256 + cc;
    for (int cl = 0; cl < 64; ++cl) {
      float hv = h[((size_t)n * CIN + cbase + cl) * HW + s0 + pl];
#pragma unroll
      for (int k = 0; k < 54; ++k) acc[k] = fmaf(hv, wlds[sl][cl][k], acc[k]);
    }
    __syncthreads();
  }
  if (sl == 1) {
#pragma unroll
    for (int k = 0; k < 54; k++) part[pl][k] = acc[k];
  }
  __syncthreads();
  if (sl == 0) {
#pragma unroll
    for (int k = 0; k < 54; k++) acc[k] += part[pl][k];
    int s = s0 + pl;
    int y = s >> 6, xx = s & 63;
    float sc[18], lo[36];
#pragma unroll
    for (int k = 0; k < 18; k++) sc[k] = acc[k] + sb[k];
#pragma unroll
    for (int k = 0; k < 36; k++) lo[k] = acc[18 + k] + lb[k];
    size_t base = (size_t)n * NANC + (size_t)s * 9;
#pragma unroll
    for (int i = 0; i < 36; i++) out[OUT_LOCS + base * 4 + i] = lo[i];
#pragma unroll
    for (int i = 0; i < 18; i++) out[OUT_SCORES + base * 2 + i] = sc[i];
    float syf = (float)(y * 16), sxf = (float)(xx * 16);
#pragma unroll
    for (int a = 0; a < 9; a++) {
      float s0v = sc[a * 2], s1v = sc[a * 2 + 1];
      float m = fmaxf(s0v, s1v);
      float e0 = expf(s0v - m), e1 = expf(s1v - m);
      float fg = e1 / (e0 + e1);
      int ri = a / 3, si = a - ri * 3;
      double r = (ri == 0) ? 0.5 : (ri == 1 ? 1.0 : 2.0);
      double scd = (si == 0) ? 8.0 : (si == 1 ? 16.0 : 32.0);
      double hhd = 16.0 * scd * sqrt(r);
      double wwd = 16.0 * scd * sqrt(1.0 / r);
      float a0 = (float)(8.0 - hhd * 0.5) + syf;
      float a1 = (float)(8.0 - wwd * 0.5) + sxf;
      float a2 = (float)(8.0 + hhd * 0.5) + syf;
      float a3 = (float)(8.0 + wwd * 0.5) + sxf;
      float hA = a2 - a0, wA = a3 - a1;
      float cy = a0 + 0.5f * hA, cx = a1 + 0.5f * wA;
      float dy = lo[a * 4 + 0], dx = lo[a * 4 + 1];
      float dh = lo[a * 4 + 2], dw = lo[a * 4 + 3];
      float cy2 = dy * hA + cy, cx2 = dx * wA + cx;
      float h2 = expf(dh) * hA, w2 = expf(dw) * wA;
      float b0 = cy2 - 0.5f * h2, b1 = cx2 - 0.5f * w2;
      float b2 = cy2 + 0.5f * h2, b3 = cx2 + 0.5f * w2;
      b0 = fminf(fmaxf(b0, 0.f), 1024.f);
      b1 = fminf(fmaxf(b1, 0.f), 1024.f);
      b2 = fminf(fmaxf(b2, 0.f), 1024.f);
      b3 = fminf(fmaxf(b3, 0.f), 1024.f);
      float hs = b2 - b0, wss = b3 - b1;
      bool valid = (hs >= 16.f) && (wss >= 16.f);
      size_t bi = base + a;
      boxes[bi * 4 + 0] = b0; boxes[bi * 4 + 1] = b1;
      boxes[bi * 4 + 2] = b2; boxes[bi * 4 + 3] = b3;
      fgm[bi] = valid ? fg : -__builtin_inff();
    }
  }
}

// ---------------- K3: top-2000 radix select + bitonic sort ----------------
__device__ __forceinline__ uint64_t make_key(const float* f, int i) {
  uint32_t s = __float_as_uint(f[i]);
  uint32_t u = (s & 0x80000000u) ? ~s : (s | 0x80000000u);
  return ((uint64_t)u << 32) | (uint32_t)(~(uint32_t)i);
}

__global__ __launch_bounds__(1024) void select_kernel(
    const float* __restrict__ fgm, uint32_t* __restrict__ sel) {
  int n = blockIdx.x;
  const float* f = fgm + (size_t)n * NANC;
  __shared__ uint32_t hist[256];
  __shared__ uint64_t keys[2048];
  __shared__ uint32_t sh_digit, sh_T, scnt;
  int tid = threadIdx.x;
  uint64_t prefix = 0;
  uint32_t T = PRE;
  for (int p = 0; p < 8; ++p) {
    int shift = 56 - 8 * p;
    if (tid < 256) hist[tid] = 0;
    __syncthreads();
    for (int i = tid; i < NANC; i += 1024) {
      uint64_t key = make_key(f, i);
      bool match = (p == 0) || ((key >> (shift + 8)) == (prefix >> (shift + 8)));
      if (match) atomicAdd(&hist[(uint32_t)(key >> shift) & 255u], 1u);
    }
    __syncthreads();
    if (tid == 0) {
      uint32_t cum = 0;
      for (int d = 255; d >= 0; --d) {
        uint32_t c = hist[d];
        if (cum + c >= T) { sh_digit = (uint32_t)d; sh_T = T - cum; break; }
        cum += c;
      }
    }
    __syncthreads();
    prefix |= ((uint64_t)sh_digit) << shift;
    T = sh_T;
    __syncthreads();
  }
  if (tid == 0) scnt = 0;
  __syncthreads();
  for (int i = tid; i < NANC; i += 1024) {
    uint64_t key = make_key(f, i);
    if (key >= prefix) {
      uint32_t pos = atomicAdd(&scnt, 1u);
      if (pos < 2048) keys[pos] = key;
    }
  }
  __syncthreads();
  for (int i = scnt + tid; i < 2048; i += 1024) keys[i] = 0;
  __syncthreads();
  for (int k = 2; k <= 2048; k <<= 1) {
    for (int j = k >> 1; j > 0; j >>= 1) {
      for (int e = tid; e < 2048; e += 1024) {
        int partner = e ^ j;
        if (partner > e) {
          bool up = ((e & k) == 0);
          uint64_t a = keys[e], b = keys[partner];
          if (up ? (a < b) : (a > b)) { keys[e] = b; keys[partner] = a; }
        }
      }
      __syncthreads();
    }
  }
  for (int t2 = tid; t2 < PRE; t2 += 1024)
    sel[n * 2048 + t2] = ~((uint32_t)(keys[t2] & 0xFFFFFFFFu));
}

// ---------------- K4: NMS + compact + write rois ----------------
__global__ __launch_bounds__(256) void nms_kernel(
    const uint32_t* __restrict__ sel, const float* __restrict__ boxes,
    const float* __restrict__ fgm, float* __restrict__ out) {
  int n = blockIdx.x;
  __shared__ float y0[PRE], x0[PRE], y1[PRE], x1[PRE], ar[PRE];
  __shared__ unsigned char keep[PRE];
  __shared__ int order[POST];
  __shared__ int cnt;
  int tid = threadIdx.x;
  for (int j = tid; j < PRE; j += 256) {
    uint32_t idx = sel[n * 2048 + j];
    const float* bp = boxes + ((size_t)n * NANC + idx) * 4;
    float a0 = bp[0], a1 = bp[1], a2 = bp[2], a3 = bp[3];
    y0[j] = a0; x0[j] = a1; y1[j] = a2; x1[j] = a3;
    ar[j] = (a2 - a0) * (a3 - a1);
    keep[j] = (fgm[(size_t)n * NANC + idx] > -__builtin_inff()) ? 1 : 0;
  }
  __syncthreads();
  for (int i = 0; i < PRE - 1; ++i) {
    if (keep[i]) {
      float iy0 = y0[i], ix0 = x0[i], iy1 = y1[i], ix1 = x1[i], iar = ar[i];
      for (int j = i + 1 + tid; j < PRE; j += 256) {
        if (!keep[j]) continue;
        float ty = fmaxf(iy0, y0[j]);
        float tx = fmaxf(ix0, x0[j]);
        float by = fminf(iy1, y1[j]);
        float bx = fminf(ix1, x1[j]);
        float ih = by - ty; if (ih < 0.f) ih = 0.f;
        float iw = bx - tx; if (iw < 0.f) iw = 0.f;
        float inter = ih * iw;
        float iou = inter / (iar + ar[j] - inter + 1e-9f);
        if (iou > 0.7f) keep[j] = 0;
      }
    }
    __syncthreads();
  }
  if (tid == 0) {
    int c = 0;
    for (int i = 0; i < PRE && c < POST; ++i)
      if (keep[i]) order[c++] = i;
    cnt = c;
  }
  __syncthreads();
  for (int r = tid; r < POST; r += 256) {
    float v0 = 0.f, v1 = 0.f, v2 = 0.f, v3 = 0.f;
    if (r < cnt) { int i = order[r]; v0 = y0[i]; v1 = x0[i]; v2 = y1[i]; v3 = x1[i]; }
    size_t o = (size_t)OUT_ROIS + ((size_t)n * POST + r) * 4;
    out[o + 0] = v0; out[o + 1] = v1; out[o + 2] = v2; out[o + 3] = v3;
    out[OUT_RIDX + n * POST + r] = (float)n;
  }
}

extern "C" void kernel_launch(void* const* d_in, const int* in_sizes, int n_in,
                              void* d_out, int out_size, void* d_ws, size_t ws_size,
                              hipStream_t stream) {
  const float* x   = (const float*)d_in[0];
  const float* c1w = (const float*)d_in[1];
  const float* c1b = (const float*)d_in[2];
  const float* sw  = (const float*)d_in[3];
  const float* sb  = (const float*)d_in[4];
  const float* lw  = (const float*)d_in[5];
  const float* lb  = (const float*)d_in[6];
  float* out = (float*)d_out;
  char* ws = (char*)d_ws;
  float* hbuf   = (float*)(ws);                    // 67108864 B
  float* fgm    = (float*)(ws + 67108864);         // 1179648*4 B
  float* boxes  = (float*)(ws + 68288512);         // 4718592*... B
  uint32_t* sel = (uint32_t*)(ws + 73007104);      // 65536 B

  anchor_kernel<<<144, 256, 0, stream>>>(out);
  conv3_kernel<<<1024, 256, 0, stream>>>(x, c1w, c1b, hbuf);
  heads_kernel<<<256, 256, 0, stream>>>(hbuf, sw, sb, lw, lb, out, fgm, boxes);
  select_kernel<<<8, 1024, 0, stream>>>(fgm, sel);
  nms_kernel<<<8, 256, 0, stream>>>(sel, boxes, fgm, out);
}

// Round 2
// 3428.737 us; speedup vs baseline: 1.4365x; 1.4365x over previous
//
#include <hip/hip_runtime.h>
#include <math.h>
#include <stdint.h>

#define NB 8
#define CIN 512
#define HW 4096
#define ANUM 9
#define NANC 36864
#define PRE 2000
#define POST 300

// d_out float offsets
#define OUT_LOCS   0
#define OUT_SCORES 1179648
#define OUT_ROIS   1769472
#define OUT_RIDX   1779072
#define OUT_ANC    1781472

// ---------------- K0: anchors ----------------
__global__ void anchor_kernel(float* __restrict__ out) {
  int i = blockIdx.x * 256 + threadIdx.x;
  if (i >= NANC) return;
  int s = i / 9, a = i - s * 9;
  int y = s >> 6, x = s & 63;
  int ri = a / 3, si = a - ri * 3;
  double r = (ri == 0) ? 0.5 : (ri == 1 ? 1.0 : 2.0);
  double sc = (si == 0) ? 8.0 : (si == 1 ? 16.0 : 32.0);
  double hh = 16.0 * sc * sqrt(r);
  double ww = 16.0 * sc * sqrt(1.0 / r);
  float a0 = (float)(8.0 - hh * 0.5);
  float a1 = (float)(8.0 - ww * 0.5);
  float a2 = (float)(8.0 + hh * 0.5);
  float a3 = (float)(8.0 + ww * 0.5);
  float sy = (float)(y * 16), sx = (float)(x * 16);
  out[OUT_ANC + i * 4 + 0] = a0 + sy;
  out[OUT_ANC + i * 4 + 1] = a1 + sx;
  out[OUT_ANC + i * 4 + 2] = a2 + sy;
  out[OUT_ANC + i * 4 + 3] = a3 + sx;
}

// ---------------- K0b: weight transpose w[oc][ic][k] -> wT[ic][k][oc] ----------------
__global__ void wt_kernel(const float* __restrict__ w, float* __restrict__ wT) {
  int i = blockIdx.x * 256 + threadIdx.x;
  if (i >= CIN * 9 * CIN) return;
  int oc = i & 511;
  int rem = i >> 9;
  int k = rem % 9;
  int ic = rem / 9;
  wT[i] = w[((size_t)oc * CIN + ic) * 9 + k];
}

// ---------------- K1: conv3x3 + bias + relu (v2: scalar weights, padded LDS) ----------------
// grid 1024: ocb(32) fastest, tile(4), n(8). 256 thr: ty=tid>>4 rows{2ty,2ty+1}, tx cols{tx,tx+16}
__global__ __launch_bounds__(256, 4) void conv3_v2(
    const float* __restrict__ x, const float* __restrict__ wT,
    const float* __restrict__ bias, float* __restrict__ h) {
  __shared__ float xs[4][34][40];  // stride 40: bank shift 16/ty-step -> 2-way (free)
  int blk = blockIdx.x;
  int ocb = blk & 31;
  int t = (blk >> 5) & 3;
  int n = blk >> 7;
  int ty0 = (t >> 1) * 32, tx0 = (t & 1) * 32;
  int tid = threadIdx.x;
  int ty = tid >> 4;
  int tx = tid & 15;

  float acc[16][4];
#pragma unroll
  for (int o = 0; o < 16; o++)
#pragma unroll
    for (int p = 0; p < 4; p++) acc[o][p] = 0.f;

  const float* xn = x + (size_t)n * CIN * HW;
  const float* wb = wT + (ocb << 4);

#pragma unroll 1
  for (int ic0 = 0; ic0 < CIN; ic0 += 4) {
    for (int l = tid; l < 4 * 34 * 34; l += 256) {
      int ic = l / 1156; int rem = l - ic * 1156;
      int dy = rem / 34; int dx = rem - dy * 34;
      int gy = ty0 - 1 + dy, gx = tx0 - 1 + dx;
      float v = 0.f;
      if ((unsigned)gy < 64u && (unsigned)gx < 64u)
        v = xn[(size_t)(ic0 + ic) * HW + (gy << 6) + gx];
      xs[ic][dy][dx] = v;
    }
    __syncthreads();
#pragma unroll 1
    for (int ic = 0; ic < 4; ++ic) {
      float xv[4][6];
#pragma unroll
      for (int r = 0; r < 4; ++r) {
#pragma unroll
        for (int c = 0; c < 3; ++c) {
          xv[r][c]     = xs[ic][2 * ty + r][tx + c];
          xv[r][3 + c] = xs[ic][2 * ty + r][tx + 16 + c];
        }
      }
      const float* wic = wb + (size_t)(ic0 + ic) * 9 * 512;
#pragma unroll
      for (int k = 0; k < 9; ++k) {
        int ky = k / 3, kx = k - ky * 3;
        const float4* wk = (const float4*)(wic + (k << 9));
        float4 w0 = wk[0], w1 = wk[1], w2 = wk[2], w3 = wk[3];
        float wv[16] = {w0.x, w0.y, w0.z, w0.w, w1.x, w1.y, w1.z, w1.w,
                        w2.x, w2.y, w2.z, w2.w, w3.x, w3.y, w3.z, w3.w};
#pragma unroll
        for (int o = 0; o < 16; ++o)
#pragma unroll
          for (int p = 0; p < 2; ++p)
#pragma unroll
            for (int q = 0; q < 2; ++q)
              acc[o][p * 2 + q] = fmaf(xv[p + ky][q * 3 + kx], wv[o], acc[o][p * 2 + q]);
      }
    }
    __syncthreads();
  }
#pragma unroll
  for (int o = 0; o < 16; o++) {
    int oc = ocb * 16 + o;
    float bv = bias[oc];
#pragma unroll
    for (int p = 0; p < 2; p++)
#pragma unroll
      for (int q = 0; q < 2; q++) {
        int gy = ty0 + 2 * ty + p, gx = tx0 + tx + 16 * q;
        float v = acc[o][p * 2 + q] + bv;
        h[((size_t)n * CIN + oc) * HW + gy * 64 + gx] = v > 0.f ? v : 0.f;
      }
  }
}

// ---------------- K2: 1x1 heads + transpose + fg + box decode ----------------
__global__ __launch_bounds__(256) void heads_kernel(
    const float* __restrict__ h, const float* __restrict__ sw,
    const float* __restrict__ sb, const float* __restrict__ lw,
    const float* __restrict__ lb, float* __restrict__ out,
    float* __restrict__ fgm, float* __restrict__ boxes) {
  __shared__ float wlds[2][64][56];
  __shared__ float part[128][56];
  int tid = threadIdx.x;
  int sl = tid >> 7;
  int pl = tid & 127;
  int blk = blockIdx.x;
  int n = blk >> 5;
  int s0 = (blk & 31) * 128;

  float acc[54];
#pragma unroll
  for (int k = 0; k < 54; k++) acc[k] = 0.f;

  for (int cc = 0; cc < 256; cc += 64) {
    for (int l = tid; l < 2 * 64 * 54; l += 256) {
      int slc = l / (64 * 54); int rem = l - slc * 64 * 54;
      int cl = rem / 54; int k = rem - cl * 54;
      int c = slc * 256 + cc + cl;
      wlds[slc][cl][k] = (k < 18) ? sw[k * CIN + c] : lw[(k - 18) * CIN + c];
    }
    __syncthreads();
    int cbase = sl * 256 + cc;
    for (int cl = 0; cl < 64; ++cl) {
      float hv = h[((size_t)n * CIN + cbase + cl) * HW + s0 + pl];
#pragma unroll
      for (int k = 0; k < 54; ++k) acc[k] = fmaf(hv, wlds[sl][cl][k], acc[k]);
    }
    __syncthreads();
  }
  if (sl == 1) {
#pragma unroll
    for (int k = 0; k < 54; k++) part[pl][k] = acc[k];
  }
  __syncthreads();
  if (sl == 0) {
#pragma unroll
    for (int k = 0; k < 54; k++) acc[k] += part[pl][k];
    int s = s0 + pl;
    int y = s >> 6, xx = s & 63;
    float sc[18], lo[36];
#pragma unroll
    for (int k = 0; k < 18; k++) sc[k] = acc[k] + sb[k];
#pragma unroll
    for (int k = 0; k < 36; k++) lo[k] = acc[18 + k] + lb[k];
    size_t base = (size_t)n * NANC + (size_t)s * 9;
#pragma unroll
    for (int i = 0; i < 36; i++) out[OUT_LOCS + base * 4 + i] = lo[i];
#pragma unroll
    for (int i = 0; i < 18; i++) out[OUT_SCORES + base * 2 + i] = sc[i];
    float syf = (float)(y * 16), sxf = (float)(xx * 16);
#pragma unroll
    for (int a = 0; a < 9; a++) {
      float s0v = sc[a * 2], s1v = sc[a * 2 + 1];
      float m = fmaxf(s0v, s1v);
      float e0 = expf(s0v - m), e1 = expf(s1v - m);
      float fg = e1 / (e0 + e1);
      int ri = a / 3, si = a - ri * 3;
      double r = (ri == 0) ? 0.5 : (ri == 1 ? 1.0 : 2.0);
      double scd = (si == 0) ? 8.0 : (si == 1 ? 16.0 : 32.0);
      double hhd = 16.0 * scd * sqrt(r);
      double wwd = 16.0 * scd * sqrt(1.0 / r);
      float a0 = (float)(8.0 - hhd * 0.5) + syf;
      float a1 = (float)(8.0 - wwd * 0.5) + sxf;
      float a2 = (float)(8.0 + hhd * 0.5) + syf;
      float a3 = (float)(8.0 + wwd * 0.5) + sxf;
      float hA = a2 - a0, wA = a3 - a1;
      float cy = a0 + 0.5f * hA, cx = a1 + 0.5f * wA;
      float dy = lo[a * 4 + 0], dx = lo[a * 4 + 1];
      float dh = lo[a * 4 + 2], dw = lo[a * 4 + 3];
      float cy2 = dy * hA + cy, cx2 = dx * wA + cx;
      float h2 = expf(dh) * hA, w2 = expf(dw) * wA;
      float b0 = cy2 - 0.5f * h2, b1 = cx2 - 0.5f * w2;
      float b2 = cy2 + 0.5f * h2, b3 = cx2 + 0.5f * w2;
      b0 = fminf(fmaxf(b0, 0.f), 1024.f);
      b1 = fminf(fmaxf(b1, 0.f), 1024.f);
      b2 = fminf(fmaxf(b2, 0.f), 1024.f);
      b3 = fminf(fmaxf(b3, 0.f), 1024.f);
      float hs = b2 - b0, wss = b3 - b1;
      bool valid = (hs >= 16.f) && (wss >= 16.f);
      size_t bi = base + a;
      boxes[bi * 4 + 0] = b0; boxes[bi * 4 + 1] = b1;
      boxes[bi * 4 + 2] = b2; boxes[bi * 4 + 3] = b3;
      fgm[bi] = valid ? fg : -__builtin_inff();
    }
  }
}

// ---------------- K3: top-2000 (4-pass radix on 32-bit orderable score) ----------------
__device__ __forceinline__ uint32_t ord32(float v) {
  uint32_t s = __float_as_uint(v);
  return (s & 0x80000000u) ? ~s : (s | 0x80000000u);
}

__global__ __launch_bounds__(1024) void select2_kernel(
    const float* __restrict__ fgm, const float* __restrict__ boxes,
    float4* __restrict__ selb, uint8_t* __restrict__ selv) {
  int n = blockIdx.x;
  const float* f = fgm + (size_t)n * NANC;
  __shared__ uint32_t hist[256];
  __shared__ uint32_t segsum[16], segsufE[16];
  __shared__ uint64_t keys[2048];
  __shared__ uint32_t sh_digit, sh_T, scnt;
  int tid = threadIdx.x;
  uint32_t pref = 0;
  uint32_t T = PRE;
  for (int p = 0; p < 4; ++p) {
    int shift = 24 - 8 * p;
    if (tid < 256) hist[tid] = 0;
    __syncthreads();
    for (int i = tid; i < NANC; i += 1024) {
      uint32_t u = ord32(f[i]);
      bool match = (p == 0) || ((u >> (shift + 8)) == (pref >> (shift + 8)));
      if (match) atomicAdd(&hist[(u >> shift) & 255u], 1u);
    }
    __syncthreads();
    if (tid < 16) {
      uint32_t s = 0;
      for (int j = 0; j < 16; ++j) s += hist[tid * 16 + j];
      segsum[tid] = s;
    }
    __syncthreads();
    if (tid == 0) {
      uint32_t run = 0;
      for (int s = 15; s >= 0; --s) { segsufE[s] = run; run += segsum[s]; }
    }
    __syncthreads();
    if (tid < 256) {
      int d = tid, s = d >> 4;
      uint32_t loc = 0;
      for (int j = d; j < (s + 1) * 16; ++j) loc += hist[j];
      uint32_t suf = segsufE[s] + loc;
      uint32_t sufn = suf - hist[d];
      if (suf >= T && sufn < T) { sh_digit = (uint32_t)d; sh_T = T - sufn; }
    }
    __syncthreads();
    pref |= sh_digit << shift;
    T = sh_T;
    __syncthreads();
  }
  if (tid == 0) scnt = 0;
  __syncthreads();
  for (int i = tid; i < NANC; i += 1024) {
    uint32_t u = ord32(f[i]);
    if (u >= pref) {
      uint32_t pos = atomicAdd(&scnt, 1u);
      if (pos < 2048) keys[pos] = ((uint64_t)u << 32) | (uint32_t)(~(uint32_t)i);
    }
  }
  __syncthreads();
  uint32_t sc = scnt > 2048 ? 2048 : scnt;
  for (int i = sc + tid; i < 2048; i += 1024) keys[i] = 0;
  __syncthreads();
  for (int k = 2; k <= 2048; k <<= 1) {
    for (int j = k >> 1; j > 0; j >>= 1) {
      for (int e = tid; e < 2048; e += 1024) {
        int partner = e ^ j;
        if (partner > e) {
          bool up = ((e & k) == 0);
          uint64_t a = keys[e], b = keys[partner];
          if (up ? (a < b) : (a > b)) { keys[e] = b; keys[partner] = a; }
        }
      }
      __syncthreads();
    }
  }
  for (int t2 = tid; t2 < PRE; t2 += 1024) {
    uint64_t key = keys[t2];
    uint32_t idx = ~((uint32_t)(key & 0xFFFFFFFFu));
    const float4* bp = (const float4*)(boxes + ((size_t)n * NANC + idx) * 4);
    selb[(size_t)n * 2048 + t2] = *bp;
    selv[(size_t)n * 2048 + t2] = ((uint32_t)(key >> 32)) > 0x007FFFFFu ? 1 : 0;
  }
}

// ---------------- K4a: NMS suppression mask (grid-parallel) ----------------
// grid 2000 = 8 n * 250; block 256 = 8 i-rows x 32 j-words
__global__ __launch_bounds__(256) void nms_mask_kernel(
    const float4* __restrict__ selb, uint64_t* __restrict__ mask) {
  __shared__ float by0[PRE], bx0_[PRE], by1[PRE], bx1_[PRE], bar[PRE];
  int b = blockIdx.x;
  int n = b / 250;
  int i0 = (b % 250) * 8;
  int tid = threadIdx.x;
  for (int j = tid; j < PRE; j += 256) {
    float4 bb = selb[(size_t)n * 2048 + j];
    by0[j] = bb.x; bx0_[j] = bb.y; by1[j] = bb.z; bx1_[j] = bb.w;
    bar[j] = (bb.z - bb.x) * (bb.w - bb.y);
  }
  __syncthreads();
  int i = i0 + (tid >> 5);
  int jw = tid & 31;
  float iy0 = by0[i], ix0 = bx0_[i], iy1 = by1[i], ix1 = bx1_[i], ia = bar[i];
  uint64_t bits = 0;
  int jb = jw * 64;
  for (int tb = 0; tb < 64; ++tb) {
    int tbp = (tb + jw) & 63;  // swizzle to avoid 64-way LDS bank conflicts
    int j = jb + tbp;
    if (j < PRE && j > i) {
      float ty = fmaxf(iy0, by0[j]);
      float txx = fmaxf(ix0, bx0_[j]);
      float byv = fminf(iy1, by1[j]);
      float bxv = fminf(ix1, bx1_[j]);
      float ih = byv - ty; if (ih < 0.f) ih = 0.f;
      float iw = bxv - txx; if (iw < 0.f) iw = 0.f;
      float inter = ih * iw;
      float iou = inter / (ia + bar[j] - inter + 1e-9f);
      if (iou > 0.7f) bits |= (1ull << tbp);
    }
  }
  mask[((size_t)n * PRE + i) * 32 + jw] = bits;
}

// ---------------- K4b: serial bit-scan NMS + write rois (1 wave / image) ----------------
__global__ __launch_bounds__(64) void nms_scan_kernel(
    const uint8_t* __restrict__ selv, const uint64_t* __restrict__ mask,
    const float4* __restrict__ selb, float* __restrict__ out) {
  int n = blockIdx.x;
  int lane = threadIdx.x;
  const uint8_t* sv = selv + (size_t)n * 2048;
  uint64_t kw = 0;
  for (int wblk = 0; wblk < 32; ++wblk) {
    int j = wblk * 64 + lane;
    bool pred = (j < PRE) && (sv[j] != 0);
    uint64_t m = __ballot(pred);
    if (lane == wblk) kw = m;
  }
  const uint64_t* mrow = mask + (size_t)n * PRE * 32;
  for (int i0 = 0; i0 < PRE; i0 += 16) {
    uint64_t rr[16];
#pragma unroll
    for (int tt = 0; tt < 16; ++tt)
      rr[tt] = (lane < 32) ? mrow[(size_t)(i0 + tt) * 32 + lane] : 0;
#pragma unroll
    for (int tt = 0; tt < 16; ++tt) {
      int i = i0 + tt;
      uint64_t w = __shfl(kw, i >> 6);
      if ((w >> (i & 63)) & 1ull) kw &= ~rr[tt];
    }
  }
  uint64_t kwv = (lane < 32) ? kw : 0ull;
  int pc = __popcll(kwv);
  int pre = pc;
  for (int d = 1; d < 64; d <<= 1) {
    int v = __shfl_up(pre, d);
    if (lane >= d) pre += v;
  }
  int total = __shfl(pre, 63);
  int rank = pre - pc;
  uint64_t bits = kwv;
  while (bits) {
    int bpos = __ffsll((unsigned long long)bits) - 1;
    bits &= bits - 1;
    if (rank < POST) {
      int j = lane * 64 + bpos;
      float4 bx = selb[(size_t)n * 2048 + j];
      size_t o = (size_t)OUT_ROIS + ((size_t)n * POST + rank) * 4;
      out[o + 0] = bx.x; out[o + 1] = bx.y; out[o + 2] = bx.z; out[o + 3] = bx.w;
    }
    rank++;
  }
  int cnt = total > POST ? POST : total;
  for (int r2 = cnt + lane; r2 < POST; r2 += 64) {
    size_t o = (size_t)OUT_ROIS + ((size_t)n * POST + r2) * 4;
    out[o + 0] = 0.f; out[o + 1] = 0.f; out[o + 2] = 0.f; out[o + 3] = 0.f;
  }
  for (int r2 = lane; r2 < POST; r2 += 64)
    out[OUT_RIDX + n * POST + r2] = (float)n;
}

extern "C" void kernel_launch(void* const* d_in, const int* in_sizes, int n_in,
                              void* d_out, int out_size, void* d_ws, size_t ws_size,
                              hipStream_t stream) {
  const float* x   = (const float*)d_in[0];
  const float* c1w = (const float*)d_in[1];
  const float* c1b = (const float*)d_in[2];
  const float* sw  = (const float*)d_in[3];
  const float* sb  = (const float*)d_in[4];
  const float* lw  = (const float*)d_in[5];
  const float* lb  = (const float*)d_in[6];
  float* out = (float*)d_out;
  char* ws = (char*)d_ws;
  float*    hbuf = (float*)(ws);                         // 67,108,864 B
  float*    fgm  = (float*)(ws + 67108864);              // 1,179,648 B
  float*    boxes= (float*)(ws + 68288512);              // 4,718,592 B
  float*    wT   = (float*)(ws + 73007104);              // 9,437,184 B
  float4*   selb = (float4*)(ws + 82444288);             // 262,144 B
  uint8_t*  selv = (uint8_t*)(ws + 82706432);            // 16,384 B
  uint64_t* mask = (uint64_t*)(ws + 82722816);           // 4,096,000 B  (end ~86.8MB)

  anchor_kernel<<<144, 256, 0, stream>>>(out);
  wt_kernel<<<9216, 256, 0, stream>>>(c1w, wT);
  conv3_v2<<<1024, 256, 0, stream>>>(x, wT, c1b, hbuf);
  heads_kernel<<<256, 256, 0, stream>>>(hbuf, sw, sb, lw, lb, out, fgm, boxes);
  select2_kernel<<<8, 1024, 0, stream>>>(fgm, boxes, selb, selv);
  nms_mask_kernel<<<2000, 256, 0, stream>>>(selb, mask);
  nms_scan_kernel<<<8, 64, 0, stream>>>(selv, mask, selb, out);
}